// Round 2
// baseline (71097.064 us; speedup 1.0000x reference)
//
#include <hip/hip_runtime.h>
#include <math.h>

// ---------------------------------------------------------------------------
// NeuralMemory (Titans-style): k/v projections -> gate scalars -> 1024-step
// sequential memory update scan (persistent kernel, state in LDS, custom grid
// barriers) -> q projection -> final retrieval MLP.
// B=8, S=1024, D=768, GH=32, THETA=0.01
// ---------------------------------------------------------------------------

#define S_LEN 1024
#define D_DIM 768
#define B_SZ 8
#define NWG 256      // scan workgroups (1 row of each matrix per wave, 3 waves)
#define NTHR 192     // 3 waves
#define THETA_F 0.01f

// ---------------------------------------------------------------------------
// Generic f32 GEMM: C[n,e] = act( sum_d A[n,d]*W[e,d] + bias[e] )
// A: [N,768], W: [768,768] row-major over d. BM=128, BN=64, BK=16, 256 thr.
// REMAP=1 stores row n=(b*1024+s) at row' = s*8+b  (k/v scan layout [S,B,D]).
// ACT=1 applies silu.
// ---------------------------------------------------------------------------
template <int ACT, int REMAP>
__global__ __launch_bounds__(256) void gemm_tn(const float* __restrict__ A,
                                               const float* __restrict__ W,
                                               const float* __restrict__ bias,
                                               float* __restrict__ C) {
  __shared__ float As[16][132];
  __shared__ float Ws[16][68];
  const int tid = threadIdx.x;
  const int txx = tid & 15, tyy = tid >> 4;
  const int eb = blockIdx.x * 64;
  const int nb = blockIdx.y * 128;
  float acc[8][4];
#pragma unroll
  for (int i = 0; i < 8; ++i)
#pragma unroll
    for (int j = 0; j < 4; ++j) acc[i][j] = 0.f;

  const int lr = tid >> 2;          // 0..63
  const int lc = (tid & 3) << 2;    // 0,4,8,12

  for (int k0 = 0; k0 < 768; k0 += 16) {
    float4 a0 = *(const float4*)(A + (size_t)(nb + lr) * 768 + k0 + lc);
    float4 a1 = *(const float4*)(A + (size_t)(nb + lr + 64) * 768 + k0 + lc);
    float4 wv = *(const float4*)(W + (size_t)(eb + lr) * 768 + k0 + lc);
    __syncthreads();
    As[lc + 0][lr] = a0.x; As[lc + 1][lr] = a0.y; As[lc + 2][lr] = a0.z; As[lc + 3][lr] = a0.w;
    As[lc + 0][lr + 64] = a1.x; As[lc + 1][lr + 64] = a1.y; As[lc + 2][lr + 64] = a1.z; As[lc + 3][lr + 64] = a1.w;
    Ws[lc + 0][lr] = wv.x; Ws[lc + 1][lr] = wv.y; Ws[lc + 2][lr] = wv.z; Ws[lc + 3][lr] = wv.w;
    __syncthreads();
#pragma unroll
    for (int kk = 0; kk < 16; ++kk) {
      float4 x0 = *(const float4*)(&As[kk][tyy * 8]);
      float4 x1 = *(const float4*)(&As[kk][tyy * 8 + 4]);
      float4 y0 = *(const float4*)(&Ws[kk][txx * 4]);
      float a8[8] = {x0.x, x0.y, x0.z, x0.w, x1.x, x1.y, x1.z, x1.w};
      float b4[4] = {y0.x, y0.y, y0.z, y0.w};
#pragma unroll
      for (int i = 0; i < 8; ++i)
#pragma unroll
        for (int j = 0; j < 4; ++j) acc[i][j] = fmaf(a8[i], b4[j], acc[i][j]);
    }
  }
  float4 bv = *(const float4*)(bias + eb + txx * 4);
#pragma unroll
  for (int i = 0; i < 8; ++i) {
    int n = nb + tyy * 8 + i;
    float4 o;
    o.x = acc[i][0] + bv.x; o.y = acc[i][1] + bv.y;
    o.z = acc[i][2] + bv.z; o.w = acc[i][3] + bv.w;
    if (ACT == 1) {
      o.x = o.x / (1.f + expf(-o.x));
      o.y = o.y / (1.f + expf(-o.y));
      o.z = o.z / (1.f + expf(-o.z));
      o.w = o.w / (1.f + expf(-o.w));
    }
    size_t row = REMAP ? (size_t)((n & 1023) * 8 + (n >> 10)) : (size_t)n;
    *(float4*)(C + row * 768 + eb + txx * 4) = o;
  }
}

// ---------------------------------------------------------------------------
// Gate scalars: alpha[t], eta[t] = mean_b sigmoid(w2 . silu(W1 @ x[b,t] + b1) + b2)
// grid = 1024 (t), block = 512 (wave = b; lanes 0-31 FG hidden, 32-63 DG hidden)
// ---------------------------------------------------------------------------
__global__ __launch_bounds__(512) void gates_kernel(
    const float* __restrict__ x, const float* __restrict__ FGW1,
    const float* __restrict__ FGb1, const float* __restrict__ FGw2,
    const float* __restrict__ FGb2, const float* __restrict__ DGW1,
    const float* __restrict__ DGb1, const float* __restrict__ DGw2,
    const float* __restrict__ DGb2, float* __restrict__ alphaA,
    float* __restrict__ etaA) {
  __shared__ float sA[8], sE[8];
  const int t = blockIdx.x, tid = threadIdx.x;
  const int b = tid >> 6, lane = tid & 63;
  const bool isFG = lane < 32;
  const int h = lane & 31;
  const float* xr = x + ((size_t)b * S_LEN + t) * D_DIM;
  const float* Wr = (isFG ? FGW1 : DGW1) + (size_t)h * D_DIM;
  float acc = 0.f;
  for (int d = 0; d < D_DIM; d += 4) {
    float4 xv = *(const float4*)(xr + d);
    float4 wv = *(const float4*)(Wr + d);
    acc = fmaf(xv.x, wv.x, acc);
    acc = fmaf(xv.y, wv.y, acc);
    acc = fmaf(xv.z, wv.z, acc);
    acc = fmaf(xv.w, wv.w, acc);
  }
  float z = acc + (isFG ? FGb1[h] : DGb1[h]);
  float sg = 1.f / (1.f + expf(-z));
  float p = z * sg * (isFG ? FGw2[h] : DGw2[h]);
  // xor offsets 16..1 keep the two 32-lane halves separate (FG | DG)
#pragma unroll
  for (int off = 16; off > 0; off >>= 1) p += __shfl_xor(p, off, 64);
  if (lane == 0) sA[b] = 1.f / (1.f + expf(-(p + FGb2[0])));
  if (lane == 32) sE[b] = 1.f / (1.f + expf(-(p + DGb2[0])));
  __syncthreads();
  if (tid == 0) {
    float sa = 0.f, se = 0.f;
#pragma unroll
    for (int i = 0; i < 8; ++i) { sa += sA[i]; se += sE[i]; }
    alphaA[t] = sa * 0.125f;
    etaA[t] = se * 0.125f;
  }
}

// ---------------------------------------------------------------------------
// Grid barrier: monotone epoch flags. Poisoned ws (0xAAAAAAAA) reads as a
// negative int => looks "not arrived" => safe; arrive[] is also zeroed by a
// memsetAsync before launch. Device-scope atomics handle XCD L2 non-coherence.
// ---------------------------------------------------------------------------
__device__ __forceinline__ void grid_barrier(int* arrive, int wg, int tid,
                                             int epoch) {
  __threadfence();   // flush my WG's global writes to agent visibility
  __syncthreads();
  if (tid == 0)
    __hip_atomic_store(arrive + wg, epoch, __ATOMIC_RELEASE,
                       __HIP_MEMORY_SCOPE_AGENT);
#pragma unroll 1
  for (int s = tid; s < NWG; s += NTHR) {
    while (__hip_atomic_load(arrive + s, __ATOMIC_RELAXED,
                             __HIP_MEMORY_SCOPE_AGENT) < epoch) {
    }
  }
  __threadfence();   // acquire: invalidate caches so normal loads see fresh data
  __syncthreads();
}

// ---------------------------------------------------------------------------
// Persistent scan kernel. 256 WGs x 192 thr (3 waves). Wave r of WG wg owns
// row jg = wg*3+r of: W1, S1, W2, S2 (row-major) and W2T, S2T (column copy of
// W2 for the backward dh1 = dOut @ W2). Lane owns 12 contiguous f32 per row.
// Per step t:
//   A: h1[b,jg] = silu(k_t[b,:] . W1[jg,:] + b1[jg])          -> global h1g
//   (barrier)
//   B: out[b] = h1[b,:] . W2[jg,:] + b2 ; dOut = c*(out - v)  -> global dOg
//      update W2 row (rank-8: dOut[b]*h1[b,:]), b2
//   (barrier)
//   C: dh1[b] = dOut[b,:] . W2T[jg,:]; dpre = dh1*silu'(pre)
//      update W1 row (dpre[b]*k[b,:]), W2T row (h1[b]*dOut[b,:]), b1
// ---------------------------------------------------------------------------
__global__ __launch_bounds__(NTHR, 1) void scan_kernel(
    const float* __restrict__ kbuf, const float* __restrict__ vbuf,
    const float* __restrict__ alphaA, const float* __restrict__ etaA,
    const float* __restrict__ MW1, const float* __restrict__ Mb1,
    const float* __restrict__ MW2, const float* __restrict__ Mb2,
    float* __restrict__ W1f, float* __restrict__ b1f, float* __restrict__ W2f,
    float* __restrict__ b2f, float* __restrict__ h1g, float* __restrict__ dOg,
    int* arrive) {
  __shared__ float sW1[3][768], sS1[3][768], sW2[3][768], sS2[3][768];
  __shared__ float sW2T[3][768], sS2T[3][768];
  __shared__ float sb1[3], ssb1[3], sb2[3], ssb2[3];

  const int tid = threadIdx.x, wg = blockIdx.x;
  const int r = tid >> 6, lane = tid & 63;
  const int jg = wg * 3 + r;
  const int colb = lane * 12;

  // ---- init state ----
  {
    const float4* s1 = (const float4*)(MW1 + (size_t)jg * 768 + colb);
    float4* d1 = (float4*)(&sW1[r][colb]);
    d1[0] = s1[0]; d1[1] = s1[1]; d1[2] = s1[2];
    const float4* s2 = (const float4*)(MW2 + (size_t)jg * 768 + colb);
    float4* d2 = (float4*)(&sW2[r][colb]);
    d2[0] = s2[0]; d2[1] = s2[1]; d2[2] = s2[2];
#pragma unroll
    for (int m = 0; m < 12; ++m)
      sW2T[r][colb + m] = MW2[(size_t)(colb + m) * 768 + jg];
    float4 z4 = {0.f, 0.f, 0.f, 0.f};
    ((float4*)&sS1[r][colb])[0] = z4; ((float4*)&sS1[r][colb])[1] = z4; ((float4*)&sS1[r][colb])[2] = z4;
    ((float4*)&sS2[r][colb])[0] = z4; ((float4*)&sS2[r][colb])[1] = z4; ((float4*)&sS2[r][colb])[2] = z4;
    ((float4*)&sS2T[r][colb])[0] = z4; ((float4*)&sS2T[r][colb])[1] = z4; ((float4*)&sS2T[r][colb])[2] = z4;
    if (lane == 0) {
      sb1[r] = Mb1[jg]; sb2[r] = Mb2[jg];
      ssb1[r] = 0.f; ssb2[r] = 0.f;
    }
  }
  __syncthreads();

  int epoch = 0;
  alignas(16) float ktv[8][12];
  float hprev[8], sgv[8], h1loc[8];
  const float c0 = 2.0f / 6144.0f;

  for (int t = 0; t < S_LEN; ++t) {
    const float a_t = alphaA[t], e_t = etaA[t];
    const float om_a = 1.0f - a_t;

    // k_t rows (kept in registers through phase C)
#pragma unroll
    for (int b = 0; b < 8; ++b) {
      const float4* kp =
          (const float4*)(kbuf + ((size_t)t * 8 + b) * 768 + colb);
      float4 k0 = kp[0], k1 = kp[1], k2 = kp[2];
      ktv[b][0] = k0.x; ktv[b][1] = k0.y; ktv[b][2] = k0.z; ktv[b][3] = k0.w;
      ktv[b][4] = k1.x; ktv[b][5] = k1.y; ktv[b][6] = k1.z; ktv[b][7] = k1.w;
      ktv[b][8] = k2.x; ktv[b][9] = k2.y; ktv[b][10] = k2.z; ktv[b][11] = k2.w;
    }

    // ---- phase A ----
    {
      alignas(16) float w1v[12];
      const float4* wp = (const float4*)(&sW1[r][colb]);
      *(float4*)&w1v[0] = wp[0]; *(float4*)&w1v[4] = wp[1]; *(float4*)&w1v[8] = wp[2];
      float acc[8] = {0, 0, 0, 0, 0, 0, 0, 0};
#pragma unroll
      for (int m = 0; m < 12; ++m)
#pragma unroll
        for (int b = 0; b < 8; ++b) acc[b] = fmaf(ktv[b][m], w1v[m], acc[b]);
#pragma unroll
      for (int off = 32; off > 0; off >>= 1)
#pragma unroll
        for (int b = 0; b < 8; ++b) acc[b] += __shfl_xor(acc[b], off, 64);
      const float b1v = sb1[r];
#pragma unroll
      for (int b = 0; b < 8; ++b) {
        float z = acc[b] + b1v;
        float sg = 1.0f / (1.0f + expf(-z));
        hprev[b] = z; sgv[b] = sg; h1loc[b] = z * sg;
      }
#pragma unroll
      for (int b = 0; b < 8; ++b)
        if (lane == b) h1g[b * 768 + jg] = h1loc[b];
    }
    grid_barrier(arrive, wg, tid, ++epoch);

    // ---- phase B ----
    {
      alignas(16) float w2v[12];
      const float4* wp = (const float4*)(&sW2[r][colb]);
      *(float4*)&w2v[0] = wp[0]; *(float4*)&w2v[4] = wp[1]; *(float4*)&w2v[8] = wp[2];
      alignas(16) float hc[8][12];
#pragma unroll
      for (int b = 0; b < 8; ++b) {
        const float4* hp = (const float4*)(h1g + b * 768 + colb);
        float4 h0 = hp[0], h1 = hp[1], h2 = hp[2];
        hc[b][0] = h0.x; hc[b][1] = h0.y; hc[b][2] = h0.z; hc[b][3] = h0.w;
        hc[b][4] = h1.x; hc[b][5] = h1.y; hc[b][6] = h1.z; hc[b][7] = h1.w;
        hc[b][8] = h2.x; hc[b][9] = h2.y; hc[b][10] = h2.z; hc[b][11] = h2.w;
      }
      float acc[8] = {0, 0, 0, 0, 0, 0, 0, 0};
#pragma unroll
      for (int m = 0; m < 12; ++m)
#pragma unroll
        for (int b = 0; b < 8; ++b) acc[b] = fmaf(hc[b][m], w2v[m], acc[b]);
#pragma unroll
      for (int off = 32; off > 0; off >>= 1)
#pragma unroll
        for (int b = 0; b < 8; ++b) acc[b] += __shfl_xor(acc[b], off, 64);
      const float b2v = sb2[r];
      float dOv[8];
#pragma unroll
      for (int b = 0; b < 8; ++b) {
        float outv = acc[b] + b2v;
        dOv[b] = c0 * (outv - vbuf[((size_t)t * 8 + b) * 768 + jg]);
      }
#pragma unroll
      for (int b = 0; b < 8; ++b)
        if (lane == b) dOg[b * 768 + jg] = dOv[b];
      // W2 row update (uses pre-update w2v already consumed)
#pragma unroll
      for (int m = 0; m < 12; ++m) {
        float g = 0.f;
#pragma unroll
        for (int b = 0; b < 8; ++b) g = fmaf(dOv[b], hc[b][m], g);
        float snew = e_t * sS2[r][colb + m] - THETA_F * g;
        sS2[r][colb + m] = snew;
        sW2[r][colb + m] = om_a * w2v[m] + snew;
      }
      if (lane == 0) {
        float gb = dOv[0] + dOv[1] + dOv[2] + dOv[3] + dOv[4] + dOv[5] + dOv[6] + dOv[7];
        float snew = e_t * ssb2[r] - THETA_F * gb;
        ssb2[r] = snew;
        sb2[r] = om_a * sb2[r] + snew;
      }
    }
    grid_barrier(arrive, wg, tid, ++epoch);

    // ---- phase C ----
    {
      alignas(16) float w2tv[12];
      const float4* wp = (const float4*)(&sW2T[r][colb]);
      *(float4*)&w2tv[0] = wp[0]; *(float4*)&w2tv[4] = wp[1]; *(float4*)&w2tv[8] = wp[2];
      alignas(16) float dc[8][12];
#pragma unroll
      for (int b = 0; b < 8; ++b) {
        const float4* dp = (const float4*)(dOg + b * 768 + colb);
        float4 d0 = dp[0], d1 = dp[1], d2 = dp[2];
        dc[b][0] = d0.x; dc[b][1] = d0.y; dc[b][2] = d0.z; dc[b][3] = d0.w;
        dc[b][4] = d1.x; dc[b][5] = d1.y; dc[b][6] = d1.z; dc[b][7] = d1.w;
        dc[b][8] = d2.x; dc[b][9] = d2.y; dc[b][10] = d2.z; dc[b][11] = d2.w;
      }
      float acc[8] = {0, 0, 0, 0, 0, 0, 0, 0};
#pragma unroll
      for (int m = 0; m < 12; ++m)
#pragma unroll
        for (int b = 0; b < 8; ++b) acc[b] = fmaf(dc[b][m], w2tv[m], acc[b]);
#pragma unroll
      for (int off = 32; off > 0; off >>= 1)
#pragma unroll
        for (int b = 0; b < 8; ++b) acc[b] += __shfl_xor(acc[b], off, 64);
      float dpre[8];
#pragma unroll
      for (int b = 0; b < 8; ++b)
        dpre[b] = acc[b] * (sgv[b] * (1.0f + hprev[b] * (1.0f - sgv[b])));
      // W1 row update
#pragma unroll
      for (int m = 0; m < 12; ++m) {
        float g = 0.f;
#pragma unroll
        for (int b = 0; b < 8; ++b) g = fmaf(dpre[b], ktv[b][m], g);
        float snew = e_t * sS1[r][colb + m] - THETA_F * g;
        sS1[r][colb + m] = snew;
        sW1[r][colb + m] = om_a * sW1[r][colb + m] + snew;
      }
      // W2T row update
#pragma unroll
      for (int m = 0; m < 12; ++m) {
        float g = 0.f;
#pragma unroll
        for (int b = 0; b < 8; ++b) g = fmaf(h1loc[b], dc[b][m], g);
        float snew = e_t * sS2T[r][colb + m] - THETA_F * g;
        sS2T[r][colb + m] = snew;
        sW2T[r][colb + m] = om_a * sW2T[r][colb + m] + snew;
      }
      if (lane == 0) {
        float gb = dpre[0] + dpre[1] + dpre[2] + dpre[3] + dpre[4] + dpre[5] + dpre[6] + dpre[7];
        float snew = e_t * ssb1[r] - THETA_F * gb;
        ssb1[r] = snew;
        sb1[r] = om_a * sb1[r] + snew;
      }
    }
    // no barrier needed before next phase A: X passing barrier2 implies every
    // WG finished phase B (h1g reads done => safe to rewrite in next A; dOg
    // rewritten only after next barrier1, by which time all phase-C reads done)
  }

  // ---- dump final params ----
  {
    float4* d1 = (float4*)(W1f + (size_t)jg * 768 + colb);
    const float4* s1 = (const float4*)(&sW1[r][colb]);
    d1[0] = s1[0]; d1[1] = s1[1]; d1[2] = s1[2];
    float4* d2 = (float4*)(W2f + (size_t)jg * 768 + colb);
    const float4* s2 = (const float4*)(&sW2[r][colb]);
    d2[0] = s2[0]; d2[1] = s2[1]; d2[2] = s2[2];
    if (lane == 0) {
      b1f[jg] = sb1[r];
      b2f[jg] = sb2[r];
    }
  }
}

// ---------------------------------------------------------------------------
extern "C" void kernel_launch(void* const* d_in, const int* in_sizes, int n_in,
                              void* d_out, int out_size, void* d_ws,
                              size_t ws_size, hipStream_t stream) {
  (void)in_sizes; (void)n_in; (void)out_size; (void)ws_size;
  const float* x   = (const float*)d_in[0];
  const float* WKw = (const float*)d_in[1];
  const float* WKb = (const float*)d_in[2];
  const float* WVw = (const float*)d_in[3];
  const float* WVb = (const float*)d_in[4];
  const float* WQw = (const float*)d_in[5];
  const float* WQb = (const float*)d_in[6];
  const float* MW1 = (const float*)d_in[7];
  const float* Mb1 = (const float*)d_in[8];
  const float* MW2 = (const float*)d_in[9];
  const float* Mb2 = (const float*)d_in[10];
  const float* FGW1 = (const float*)d_in[11];
  const float* FGb1 = (const float*)d_in[12];
  const float* FGw2 = (const float*)d_in[13];
  const float* FGb2 = (const float*)d_in[14];
  const float* DGW1 = (const float*)d_in[15];
  const float* DGb1 = (const float*)d_in[16];
  const float* DGw2 = (const float*)d_in[17];
  const float* DGb2 = (const float*)d_in[18];
  float* out = (float*)d_out;

  // workspace layout (floats). k/v needed only through the scan; q and h1 are
  // computed AFTER the scan and alias the k/v regions (x is never modified).
  float* ws = (float*)d_ws;
  float* kbuf = ws;                       // [S,B,D]  6291456 f32
  float* vbuf = ws + 6291456;             // [S,B,D]  6291456 f32
  float* W1f  = ws + 12582912;            // [768,768]
  float* W2f  = W1f + 589824;
  float* b1f  = W2f + 589824;             // [768]
  float* b2f  = b1f + 768;
  float* alphaA = b2f + 768;              // [1024]
  float* etaA   = alphaA + 1024;
  float* h1g  = etaA + 1024;              // [8,768]
  float* dOg  = h1g + 6144;               // [8,768]
  int* arrive = (int*)(dOg + 6144);       // [NWG]
  float* qbuf = kbuf;                     // reuse k region after scan
  float* h1q  = vbuf;                     // reuse v region after scan
  // total ~13.8M f32 ~= 55.3 MB

  hipMemsetAsync(arrive, 0, NWG * sizeof(int), stream);

  dim3 gg(12, 64), bb(256);
  gemm_tn<0, 1><<<gg, bb, 0, stream>>>(x, WKw, WKb, kbuf);
  gemm_tn<0, 1><<<gg, bb, 0, stream>>>(x, WVw, WVb, vbuf);
  gates_kernel<<<dim3(1024), dim3(512), 0, stream>>>(
      x, FGW1, FGb1, FGw2, FGb2, DGW1, DGb1, DGw2, DGb2, alphaA, etaA);
  scan_kernel<<<dim3(NWG), dim3(NTHR), 0, stream>>>(
      kbuf, vbuf, alphaA, etaA, MW1, Mb1, MW2, Mb2, W1f, b1f, W2f, b2f, h1g,
      dOg, arrive);
  gemm_tn<0, 0><<<gg, bb, 0, stream>>>(x, WQw, WQb, qbuf);
  gemm_tn<1, 0><<<gg, bb, 0, stream>>>(qbuf, W1f, b1f, h1q);
  gemm_tn<0, 0><<<gg, bb, 0, stream>>>(h1q, W2f, b2f, out);
}

// Round 8
// 67105.676 us; speedup vs baseline: 1.0595x; 1.0595x over previous
//
#include <hip/hip_runtime.h>
#include <math.h>

// ---------------------------------------------------------------------------
// NeuralMemory (Titans-style): k/v projections -> gate scalars -> 1024-step
// sequential memory update scan (persistent kernel, state in LDS, custom grid
// barriers) -> q projection -> final retrieval MLP.
// B=8, S=1024, D=768, GH=32, THETA=0.01
//
// Round 3..8: master/broadcast grid barrier (was symmetric all-poll-all, 34us
// per barrier, 548MB poll traffic). Only WG0 polls arrival flags; others spin
// on a single 'go' epoch line with s_sleep backoff.
// ---------------------------------------------------------------------------

#define S_LEN 1024
#define D_DIM 768
#define B_SZ 8
#define NWG 256      // scan workgroups (1 row of each matrix per wave, 3 waves)
#define NTHR 192     // 3 waves
#define THETA_F 0.01f
#define FLAG_STRIDE 16   // one 64B cacheline per arrival flag

// ---------------------------------------------------------------------------
// Generic f32 GEMM: C[n,e] = act( sum_d A[n,d]*W[e,d] + bias[e] )
// A: [N,768], W: [768,768] row-major over d. BM=128, BN=64, BK=16, 256 thr.
// REMAP=1 stores row n=(b*1024+s) at row' = s*8+b  (k/v scan layout [S,B,D]).
// ACT=1 applies silu.
// ---------------------------------------------------------------------------
template <int ACT, int REMAP>
__global__ __launch_bounds__(256) void gemm_tn(const float* __restrict__ A,
                                               const float* __restrict__ W,
                                               const float* __restrict__ bias,
                                               float* __restrict__ C) {
  __shared__ float As[16][132];
  __shared__ float Ws[16][68];
  const int tid = threadIdx.x;
  const int txx = tid & 15, tyy = tid >> 4;
  const int eb = blockIdx.x * 64;
  const int nb = blockIdx.y * 128;
  float acc[8][4];
#pragma unroll
  for (int i = 0; i < 8; ++i)
#pragma unroll
    for (int j = 0; j < 4; ++j) acc[i][j] = 0.f;

  const int lr = tid >> 2;          // 0..63
  const int lc = (tid & 3) << 2;    // 0,4,8,12

  for (int k0 = 0; k0 < 768; k0 += 16) {
    float4 a0 = *(const float4*)(A + (size_t)(nb + lr) * 768 + k0 + lc);
    float4 a1 = *(const float4*)(A + (size_t)(nb + lr + 64) * 768 + k0 + lc);
    float4 wv = *(const float4*)(W + (size_t)(eb + lr) * 768 + k0 + lc);
    __syncthreads();
    As[lc + 0][lr] = a0.x; As[lc + 1][lr] = a0.y; As[lc + 2][lr] = a0.z; As[lc + 3][lr] = a0.w;
    As[lc + 0][lr + 64] = a1.x; As[lc + 1][lr + 64] = a1.y; As[lc + 2][lr + 64] = a1.z; As[lc + 3][lr + 64] = a1.w;
    Ws[lc + 0][lr] = wv.x; Ws[lc + 1][lr] = wv.y; Ws[lc + 2][lr] = wv.z; Ws[lc + 3][lr] = wv.w;
    __syncthreads();
#pragma unroll
    for (int kk = 0; kk < 16; ++kk) {
      float4 x0 = *(const float4*)(&As[kk][tyy * 8]);
      float4 x1 = *(const float4*)(&As[kk][tyy * 8 + 4]);
      float4 y0 = *(const float4*)(&Ws[kk][txx * 4]);
      float a8[8] = {x0.x, x0.y, x0.z, x0.w, x1.x, x1.y, x1.z, x1.w};
      float b4[4] = {y0.x, y0.y, y0.z, y0.w};
#pragma unroll
      for (int i = 0; i < 8; ++i)
#pragma unroll
        for (int j = 0; j < 4; ++j) acc[i][j] = fmaf(a8[i], b4[j], acc[i][j]);
    }
  }
  float4 bv = *(const float4*)(bias + eb + txx * 4);
#pragma unroll
  for (int i = 0; i < 8; ++i) {
    int n = nb + tyy * 8 + i;
    float4 o;
    o.x = acc[i][0] + bv.x; o.y = acc[i][1] + bv.y;
    o.z = acc[i][2] + bv.z; o.w = acc[i][3] + bv.w;
    if (ACT == 1) {
      o.x = o.x / (1.f + expf(-o.x));
      o.y = o.y / (1.f + expf(-o.y));
      o.z = o.z / (1.f + expf(-o.z));
      o.w = o.w / (1.f + expf(-o.w));
    }
    size_t row = REMAP ? (size_t)((n & 1023) * 8 + (n >> 10)) : (size_t)n;
    *(float4*)(C + row * 768 + eb + txx * 4) = o;
  }
}

// ---------------------------------------------------------------------------
// Gate scalars: alpha[t], eta[t] = mean_b sigmoid(w2 . silu(W1 @ x[b,t] + b1) + b2)
// grid = 1024 (t), block = 512 (wave = b; lanes 0-31 FG hidden, 32-63 DG hidden)
// ---------------------------------------------------------------------------
__global__ __launch_bounds__(512) void gates_kernel(
    const float* __restrict__ x, const float* __restrict__ FGW1,
    const float* __restrict__ FGb1, const float* __restrict__ FGw2,
    const float* __restrict__ FGb2, const float* __restrict__ DGW1,
    const float* __restrict__ DGb1, const float* __restrict__ DGw2,
    const float* __restrict__ DGb2, float* __restrict__ alphaA,
    float* __restrict__ etaA) {
  __shared__ float sA[8], sE[8];
  const int t = blockIdx.x, tid = threadIdx.x;
  const int b = tid >> 6, lane = tid & 63;
  const bool isFG = lane < 32;
  const int h = lane & 31;
  const float* xr = x + ((size_t)b * S_LEN + t) * D_DIM;
  const float* Wr = (isFG ? FGW1 : DGW1) + (size_t)h * D_DIM;
  float acc = 0.f;
  for (int d = 0; d < D_DIM; d += 4) {
    float4 xv = *(const float4*)(xr + d);
    float4 wv = *(const float4*)(Wr + d);
    acc = fmaf(xv.x, wv.x, acc);
    acc = fmaf(xv.y, wv.y, acc);
    acc = fmaf(xv.z, wv.z, acc);
    acc = fmaf(xv.w, wv.w, acc);
  }
  float z = acc + (isFG ? FGb1[h] : DGb1[h]);
  float sg = 1.f / (1.f + expf(-z));
  float p = z * sg * (isFG ? FGw2[h] : DGw2[h]);
  // xor offsets 16..1 keep the two 32-lane halves separate (FG | DG)
#pragma unroll
  for (int off = 16; off > 0; off >>= 1) p += __shfl_xor(p, off, 64);
  if (lane == 0) sA[b] = 1.f / (1.f + expf(-(p + FGb2[0])));
  if (lane == 32) sE[b] = 1.f / (1.f + expf(-(p + DGb2[0])));
  __syncthreads();
  if (tid == 0) {
    float sa = 0.f, se = 0.f;
#pragma unroll
    for (int i = 0; i < 8; ++i) { sa += sA[i]; se += sE[i]; }
    alphaA[t] = sa * 0.125f;
    etaA[t] = se * 0.125f;
  }
}

// ---------------------------------------------------------------------------
// Master/broadcast grid barrier, monotone epochs.
//  - each WG (except 0): tid0 stores arrive[wg] = epoch (own 64B line),
//    then spins on the single 'go' line until go >= epoch.
//  - WG 0: its 192 threads poll the 255 arrival flags (1-2 each), then tid0
//    publishes go = epoch.
// Poisoned ws (0xAAAAAAAA) reads as negative => "not arrived" => safe; the
// region is also zeroed by memsetAsync before launch. Fences (agent scope)
// on both sides handle XCD L2 non-coherence for the normal h1g/dOg traffic.
// ---------------------------------------------------------------------------
__device__ __forceinline__ void grid_barrier(int* arrive, int* go, int wg,
                                             int tid, int epoch) {
  __threadfence();   // release my WG's global writes to agent scope
  __syncthreads();
  if (wg == 0) {
    // threads 0..191 poll flags 1..192; threads 0..62 also poll 193..255
#pragma unroll 1
    for (int s = tid + 1; s < NWG; s += NTHR) {
      while (__hip_atomic_load(arrive + s * FLAG_STRIDE, __ATOMIC_RELAXED,
                               __HIP_MEMORY_SCOPE_AGENT) < epoch) {
        __builtin_amdgcn_s_sleep(1);
      }
    }
    __syncthreads();
    if (tid == 0)
      __hip_atomic_store(go, epoch, __ATOMIC_RELEASE,
                         __HIP_MEMORY_SCOPE_AGENT);
  } else {
    if (tid == 0) {
      __hip_atomic_store(arrive + wg * FLAG_STRIDE, epoch, __ATOMIC_RELEASE,
                         __HIP_MEMORY_SCOPE_AGENT);
      while (__hip_atomic_load(go, __ATOMIC_RELAXED,
                               __HIP_MEMORY_SCOPE_AGENT) < epoch) {
        __builtin_amdgcn_s_sleep(1);
      }
    }
    __syncthreads();
  }
  __threadfence();   // acquire: invalidate so normal loads see fresh data
}

// ---------------------------------------------------------------------------
// Persistent scan kernel. 256 WGs x 192 thr (3 waves). Wave r of WG wg owns
// row jg = wg*3+r of: W1, S1, W2, S2 (row-major) and W2T, S2T (column copy of
// W2 for the backward dh1 = dOut @ W2). Lane owns 12 contiguous f32 per row.
// Per step t:
//   A: h1[b,jg] = silu(k_t[b,:] . W1[jg,:] + b1[jg])          -> global h1g
//   (barrier)
//   B: out[b] = h1[b,:] . W2[jg,:] + b2 ; dOut = c*(out - v)  -> global dOg
//      update W2 row (rank-8: dOut[b]*h1[b,:]), b2
//   (barrier)
//   C: dh1[b] = dOut[b,:] . W2T[jg,:]; dpre = dh1*silu'(pre)
//      update W1 row (dpre[b]*k[b,:]), W2T row (h1[b]*dOut[b,:]), b1
// ---------------------------------------------------------------------------
__global__ __launch_bounds__(NTHR, 1) void scan_kernel(
    const float* __restrict__ kbuf, const float* __restrict__ vbuf,
    const float* __restrict__ alphaA, const float* __restrict__ etaA,
    const float* __restrict__ MW1, const float* __restrict__ Mb1,
    const float* __restrict__ MW2, const float* __restrict__ Mb2,
    float* __restrict__ W1f, float* __restrict__ b1f, float* __restrict__ W2f,
    float* __restrict__ b2f, float* __restrict__ h1g, float* __restrict__ dOg,
    int* arrive, int* go) {
  __shared__ float sW1[3][768], sS1[3][768], sW2[3][768], sS2[3][768];
  __shared__ float sW2T[3][768], sS2T[3][768];
  __shared__ float sb1[3], ssb1[3], sb2[3], ssb2[3];

  const int tid = threadIdx.x, wg = blockIdx.x;
  const int r = tid >> 6, lane = tid & 63;
  const int jg = wg * 3 + r;
  const int colb = lane * 12;

  // ---- init state ----
  {
    const float4* s1 = (const float4*)(MW1 + (size_t)jg * 768 + colb);
    float4* d1 = (float4*)(&sW1[r][colb]);
    d1[0] = s1[0]; d1[1] = s1[1]; d1[2] = s1[2];
    const float4* s2 = (const float4*)(MW2 + (size_t)jg * 768 + colb);
    float4* d2 = (float4*)(&sW2[r][colb]);
    d2[0] = s2[0]; d2[1] = s2[1]; d2[2] = s2[2];
#pragma unroll
    for (int m = 0; m < 12; ++m)
      sW2T[r][colb + m] = MW2[(size_t)(colb + m) * 768 + jg];
    float4 z4 = {0.f, 0.f, 0.f, 0.f};
    ((float4*)&sS1[r][colb])[0] = z4; ((float4*)&sS1[r][colb])[1] = z4; ((float4*)&sS1[r][colb])[2] = z4;
    ((float4*)&sS2[r][colb])[0] = z4; ((float4*)&sS2[r][colb])[1] = z4; ((float4*)&sS2[r][colb])[2] = z4;
    ((float4*)&sS2T[r][colb])[0] = z4; ((float4*)&sS2T[r][colb])[1] = z4; ((float4*)&sS2T[r][colb])[2] = z4;
    if (lane == 0) {
      sb1[r] = Mb1[jg]; sb2[r] = Mb2[jg];
      ssb1[r] = 0.f; ssb2[r] = 0.f;
    }
  }
  __syncthreads();

  int epoch = 0;
  alignas(16) float ktv[8][12];
  float hprev[8], sgv[8], h1loc[8];
  const float c0 = 2.0f / 6144.0f;

  for (int t = 0; t < S_LEN; ++t) {
    const float a_t = alphaA[t], e_t = etaA[t];
    const float om_a = 1.0f - a_t;

    // k_t rows (kept in registers through phase C)
#pragma unroll
    for (int b = 0; b < 8; ++b) {
      const float4* kp =
          (const float4*)(kbuf + ((size_t)t * 8 + b) * 768 + colb);
      float4 k0 = kp[0], k1 = kp[1], k2 = kp[2];
      ktv[b][0] = k0.x; ktv[b][1] = k0.y; ktv[b][2] = k0.z; ktv[b][3] = k0.w;
      ktv[b][4] = k1.x; ktv[b][5] = k1.y; ktv[b][6] = k1.z; ktv[b][7] = k1.w;
      ktv[b][8] = k2.x; ktv[b][9] = k2.y; ktv[b][10] = k2.z; ktv[b][11] = k2.w;
    }

    // ---- phase A ----
    {
      alignas(16) float w1v[12];
      const float4* wp = (const float4*)(&sW1[r][colb]);
      *(float4*)&w1v[0] = wp[0]; *(float4*)&w1v[4] = wp[1]; *(float4*)&w1v[8] = wp[2];
      float acc[8] = {0, 0, 0, 0, 0, 0, 0, 0};
#pragma unroll
      for (int m = 0; m < 12; ++m)
#pragma unroll
        for (int b = 0; b < 8; ++b) acc[b] = fmaf(ktv[b][m], w1v[m], acc[b]);
#pragma unroll
      for (int off = 32; off > 0; off >>= 1)
#pragma unroll
        for (int b = 0; b < 8; ++b) acc[b] += __shfl_xor(acc[b], off, 64);
      const float b1v = sb1[r];
#pragma unroll
      for (int b = 0; b < 8; ++b) {
        float z = acc[b] + b1v;
        float sg = 1.0f / (1.0f + expf(-z));
        hprev[b] = z; sgv[b] = sg; h1loc[b] = z * sg;
      }
#pragma unroll
      for (int b = 0; b < 8; ++b)
        if (lane == b) h1g[b * 768 + jg] = h1loc[b];
    }
    grid_barrier(arrive, go, wg, tid, ++epoch);

    // ---- phase B ----
    {
      alignas(16) float w2v[12];
      const float4* wp = (const float4*)(&sW2[r][colb]);
      *(float4*)&w2v[0] = wp[0]; *(float4*)&w2v[4] = wp[1]; *(float4*)&w2v[8] = wp[2];
      alignas(16) float hc[8][12];
#pragma unroll
      for (int b = 0; b < 8; ++b) {
        const float4* hp = (const float4*)(h1g + b * 768 + colb);
        float4 h0 = hp[0], h1 = hp[1], h2 = hp[2];
        hc[b][0] = h0.x; hc[b][1] = h0.y; hc[b][2] = h0.z; hc[b][3] = h0.w;
        hc[b][4] = h1.x; hc[b][5] = h1.y; hc[b][6] = h1.z; hc[b][7] = h1.w;
        hc[b][8] = h2.x; hc[b][9] = h2.y; hc[b][10] = h2.z; hc[b][11] = h2.w;
      }
      float acc[8] = {0, 0, 0, 0, 0, 0, 0, 0};
#pragma unroll
      for (int m = 0; m < 12; ++m)
#pragma unroll
        for (int b = 0; b < 8; ++b) acc[b] = fmaf(hc[b][m], w2v[m], acc[b]);
#pragma unroll
      for (int off = 32; off > 0; off >>= 1)
#pragma unroll
        for (int b = 0; b < 8; ++b) acc[b] += __shfl_xor(acc[b], off, 64);
      const float b2v = sb2[r];
      float dOv[8];
#pragma unroll
      for (int b = 0; b < 8; ++b) {
        float outv = acc[b] + b2v;
        dOv[b] = c0 * (outv - vbuf[((size_t)t * 8 + b) * 768 + jg]);
      }
#pragma unroll
      for (int b = 0; b < 8; ++b)
        if (lane == b) dOg[b * 768 + jg] = dOv[b];
      // W2 row update (uses pre-update w2v already consumed)
#pragma unroll
      for (int m = 0; m < 12; ++m) {
        float g = 0.f;
#pragma unroll
        for (int b = 0; b < 8; ++b) g = fmaf(dOv[b], hc[b][m], g);
        float snew = e_t * sS2[r][colb + m] - THETA_F * g;
        sS2[r][colb + m] = snew;
        sW2[r][colb + m] = om_a * w2v[m] + snew;
      }
      if (lane == 0) {
        float gb = dOv[0] + dOv[1] + dOv[2] + dOv[3] + dOv[4] + dOv[5] + dOv[6] + dOv[7];
        float snew = e_t * ssb2[r] - THETA_F * gb;
        ssb2[r] = snew;
        sb2[r] = om_a * sb2[r] + snew;
      }
    }
    grid_barrier(arrive, go, wg, tid, ++epoch);

    // ---- phase C ----
    {
      alignas(16) float w2tv[12];
      const float4* wp = (const float4*)(&sW2T[r][colb]);
      *(float4*)&w2tv[0] = wp[0]; *(float4*)&w2tv[4] = wp[1]; *(float4*)&w2tv[8] = wp[2];
      alignas(16) float dc[8][12];
#pragma unroll
      for (int b = 0; b < 8; ++b) {
        const float4* dp = (const float4*)(dOg + b * 768 + colb);
        float4 d0 = dp[0], d1 = dp[1], d2 = dp[2];
        dc[b][0] = d0.x; dc[b][1] = d0.y; dc[b][2] = d0.z; dc[b][3] = d0.w;
        dc[b][4] = d1.x; dc[b][5] = d1.y; dc[b][6] = d1.z; dc[b][7] = d1.w;
        dc[b][8] = d2.x; dc[b][9] = d2.y; dc[b][10] = d2.z; dc[b][11] = d2.w;
      }
      float acc[8] = {0, 0, 0, 0, 0, 0, 0, 0};
#pragma unroll
      for (int m = 0; m < 12; ++m)
#pragma unroll
        for (int b = 0; b < 8; ++b) acc[b] = fmaf(dc[b][m], w2tv[m], acc[b]);
#pragma unroll
      for (int off = 32; off > 0; off >>= 1)
#pragma unroll
        for (int b = 0; b < 8; ++b) acc[b] += __shfl_xor(acc[b], off, 64);
      float dpre[8];
#pragma unroll
      for (int b = 0; b < 8; ++b)
        dpre[b] = acc[b] * (sgv[b] * (1.0f + hprev[b] * (1.0f - sgv[b])));
      // W1 row update
#pragma unroll
      for (int m = 0; m < 12; ++m) {
        float g = 0.f;
#pragma unroll
        for (int b = 0; b < 8; ++b) g = fmaf(dpre[b], ktv[b][m], g);
        float snew = e_t * sS1[r][colb + m] - THETA_F * g;
        sS1[r][colb + m] = snew;
        sW1[r][colb + m] = om_a * sW1[r][colb + m] + snew;
      }
      // W2T row update
#pragma unroll
      for (int m = 0; m < 12; ++m) {
        float g = 0.f;
#pragma unroll
        for (int b = 0; b < 8; ++b) g = fmaf(h1loc[b], dc[b][m], g);
        float snew = e_t * sS2T[r][colb + m] - THETA_F * g;
        sS2T[r][colb + m] = snew;
        sW2T[r][colb + m] = om_a * sW2T[r][colb + m] + snew;
      }
      if (lane == 0) {
        float gb = dpre[0] + dpre[1] + dpre[2] + dpre[3] + dpre[4] + dpre[5] + dpre[6] + dpre[7];
        float snew = e_t * ssb1[r] - THETA_F * gb;
        ssb1[r] = snew;
        sb1[r] = om_a * sb1[r] + snew;
      }
    }
    // no barrier needed before next phase A: a WG passing barrier2 implies
    // every WG finished phase B (h1g reads done => safe to rewrite in next A;
    // dOg rewritten only after next barrier1, when all phase-C reads are done)
  }

  // ---- dump final params ----
  {
    float4* d1 = (float4*)(W1f + (size_t)jg * 768 + colb);
    const float4* s1 = (const float4*)(&sW1[r][colb]);
    d1[0] = s1[0]; d1[1] = s1[1]; d1[2] = s1[2];
    float4* d2 = (float4*)(W2f + (size_t)jg * 768 + colb);
    const float4* s2 = (const float4*)(&sW2[r][colb]);
    d2[0] = s2[0]; d2[1] = s2[1]; d2[2] = s2[2];
    if (lane == 0) {
      b1f[jg] = sb1[r];
      b2f[jg] = sb2[r];
    }
  }
}

// ---------------------------------------------------------------------------
extern "C" void kernel_launch(void* const* d_in, const int* in_sizes, int n_in,
                              void* d_out, int out_size, void* d_ws,
                              size_t ws_size, hipStream_t stream) {
  (void)in_sizes; (void)n_in; (void)out_size; (void)ws_size;
  const float* x   = (const float*)d_in[0];
  const float* WKw = (const float*)d_in[1];
  const float* WKb = (const float*)d_in[2];
  const float* WVw = (const float*)d_in[3];
  const float* WVb = (const float*)d_in[4];
  const float* WQw = (const float*)d_in[5];
  const float* WQb = (const float*)d_in[6];
  const float* MW1 = (const float*)d_in[7];
  const float* Mb1 = (const float*)d_in[8];
  const float* MW2 = (const float*)d_in[9];
  const float* Mb2 = (const float*)d_in[10];
  const float* FGW1 = (const float*)d_in[11];
  const float* FGb1 = (const float*)d_in[12];
  const float* FGw2 = (const float*)d_in[13];
  const float* FGb2 = (const float*)d_in[14];
  const float* DGW1 = (const float*)d_in[15];
  const float* DGb1 = (const float*)d_in[16];
  const float* DGw2 = (const float*)d_in[17];
  const float* DGb2 = (const float*)d_in[18];
  float* out = (float*)d_out;

  // workspace layout (floats). k/v needed only through the scan; q and h1 are
  // computed AFTER the scan and alias the k/v regions (x is never modified).
  float* ws = (float*)d_ws;
  float* kbuf = ws;                       // [S,B,D]  6291456 f32
  float* vbuf = ws + 6291456;             // [S,B,D]  6291456 f32
  float* W1f  = ws + 12582912;            // [768,768]
  float* W2f  = W1f + 589824;
  float* b1f  = W2f + 589824;             // [768]
  float* b2f  = b1f + 768;
  float* alphaA = b2f + 768;              // [1024]
  float* etaA   = alphaA + 1024;
  float* h1g  = etaA + 1024;              // [8,768]
  float* dOg  = h1g + 6144;               // [8,768]
  int* arrive = (int*)(dOg + 6144);       // [NWG*FLAG_STRIDE] (64B/flag)
  int* go     = arrive + NWG * FLAG_STRIDE;  // own cacheline
  float* qbuf = kbuf;                     // reuse k region after scan
  float* h1q  = vbuf;                     // reuse v region after scan
  // total ~13.8M f32 ~= 55.4 MB

  hipMemsetAsync(arrive, 0, (NWG * FLAG_STRIDE + FLAG_STRIDE) * sizeof(int),
                 stream);

  dim3 gg(12, 64), bb(256);
  gemm_tn<0, 1><<<gg, bb, 0, stream>>>(x, WKw, WKb, kbuf);
  gemm_tn<0, 1><<<gg, bb, 0, stream>>>(x, WVw, WVb, vbuf);
  gates_kernel<<<dim3(1024), dim3(512), 0, stream>>>(
      x, FGW1, FGb1, FGw2, FGb2, DGW1, DGb1, DGw2, DGb2, alphaA, etaA);
  scan_kernel<<<dim3(NWG), dim3(NTHR), 0, stream>>>(
      kbuf, vbuf, alphaA, etaA, MW1, Mb1, MW2, Mb2, W1f, b1f, W2f, b2f, h1g,
      dOg, arrive, go);
  gemm_tn<0, 0><<<gg, bb, 0, stream>>>(x, WQw, WQb, qbuf);
  gemm_tn<1, 0><<<gg, bb, 0, stream>>>(qbuf, W1f, b1f, h1q);
  gemm_tn<0, 0><<<gg, bb, 0, stream>>>(h1q, W2f, b2f, out);
}

// Round 9
// 23139.517 us; speedup vs baseline: 3.0725x; 2.9000x over previous
//
#include <hip/hip_runtime.h>
#include <math.h>

// ---------------------------------------------------------------------------
// NeuralMemory (Titans-style). Round 9 redesign:
// The persistent-kernel scan was NOT poll-bound: changing poll topology 200x
// (round 2 -> round 8) left it at ~45us/barrier, VALUBusy 2.2%. Diagnosis:
// per-wave __threadfence() => buffer_wbl2/buffer_inv (full per-XCD L2
// writeback+invalidate) x 768 waves x 2 fences x 2048 barriers, serializing
// at the 8 TCCs (~45us/barrier fixed). Fix: use KERNEL BOUNDARIES as the
// grid barrier -- the packet processor does the L2 flush once per dispatch
// (~2-4us). 2 kernels per scan step, 2051 micro-dispatches in the graph.
// State (W1,S1,W2,S2,W2T,S2T, biases) lives in global memory (13.8MB, fully
// LLC-resident). Phase C of step t-1 is fused into the phase-A kernel of
// step t (both wave-local given dOut).
// B=8, S=1024, D=768, GH=32, THETA=0.01
// ---------------------------------------------------------------------------

#define S_LEN 1024
#define D_DIM 768
#define THETA_F 0.01f
#define NWG_S 96     // step kernels: 96 WGs x 8 waves = 768 waves (1 row each)
#define NTHR_S 512

// ---------------------------------------------------------------------------
// Generic f32 GEMM: C[n,e] = act( sum_d A[n,d]*W[e,d] + bias[e] )
// A: [N,768], W: [768,768] row-major over d. BM=128, BN=64, BK=16, 256 thr.
// REMAP=1 stores row n=(b*1024+s) at row' = s*8+b  (k/v scan layout [S,B,D]).
// ACT=1 applies silu.  (unchanged from round 2; validated)
// ---------------------------------------------------------------------------
template <int ACT, int REMAP>
__global__ __launch_bounds__(256) void gemm_tn(const float* __restrict__ A,
                                               const float* __restrict__ W,
                                               const float* __restrict__ bias,
                                               float* __restrict__ C) {
  __shared__ float As[16][132];
  __shared__ float Ws[16][68];
  const int tid = threadIdx.x;
  const int txx = tid & 15, tyy = tid >> 4;
  const int eb = blockIdx.x * 64;
  const int nb = blockIdx.y * 128;
  float acc[8][4];
#pragma unroll
  for (int i = 0; i < 8; ++i)
#pragma unroll
    for (int j = 0; j < 4; ++j) acc[i][j] = 0.f;

  const int lr = tid >> 2;          // 0..63
  const int lc = (tid & 3) << 2;    // 0,4,8,12

  for (int k0 = 0; k0 < 768; k0 += 16) {
    float4 a0 = *(const float4*)(A + (size_t)(nb + lr) * 768 + k0 + lc);
    float4 a1 = *(const float4*)(A + (size_t)(nb + lr + 64) * 768 + k0 + lc);
    float4 wv = *(const float4*)(W + (size_t)(eb + lr) * 768 + k0 + lc);
    __syncthreads();
    As[lc + 0][lr] = a0.x; As[lc + 1][lr] = a0.y; As[lc + 2][lr] = a0.z; As[lc + 3][lr] = a0.w;
    As[lc + 0][lr + 64] = a1.x; As[lc + 1][lr + 64] = a1.y; As[lc + 2][lr + 64] = a1.z; As[lc + 3][lr + 64] = a1.w;
    Ws[lc + 0][lr] = wv.x; Ws[lc + 1][lr] = wv.y; Ws[lc + 2][lr] = wv.z; Ws[lc + 3][lr] = wv.w;
    __syncthreads();
#pragma unroll
    for (int kk = 0; kk < 16; ++kk) {
      float4 x0 = *(const float4*)(&As[kk][tyy * 8]);
      float4 x1 = *(const float4*)(&As[kk][tyy * 8 + 4]);
      float4 y0 = *(const float4*)(&Ws[kk][txx * 4]);
      float a8[8] = {x0.x, x0.y, x0.z, x0.w, x1.x, x1.y, x1.z, x1.w};
      float b4[4] = {y0.x, y0.y, y0.z, y0.w};
#pragma unroll
      for (int i = 0; i < 8; ++i)
#pragma unroll
        for (int j = 0; j < 4; ++j) acc[i][j] = fmaf(a8[i], b4[j], acc[i][j]);
    }
  }
  float4 bv = *(const float4*)(bias + eb + txx * 4);
#pragma unroll
  for (int i = 0; i < 8; ++i) {
    int n = nb + tyy * 8 + i;
    float4 o;
    o.x = acc[i][0] + bv.x; o.y = acc[i][1] + bv.y;
    o.z = acc[i][2] + bv.z; o.w = acc[i][3] + bv.w;
    if (ACT == 1) {
      o.x = o.x / (1.f + expf(-o.x));
      o.y = o.y / (1.f + expf(-o.y));
      o.z = o.z / (1.f + expf(-o.z));
      o.w = o.w / (1.f + expf(-o.w));
    }
    size_t row = REMAP ? (size_t)((n & 1023) * 8 + (n >> 10)) : (size_t)n;
    *(float4*)(C + row * 768 + eb + txx * 4) = o;
  }
}

// ---------------------------------------------------------------------------
// Gate scalars (unchanged; validated)
// ---------------------------------------------------------------------------
__global__ __launch_bounds__(512) void gates_kernel(
    const float* __restrict__ x, const float* __restrict__ FGW1,
    const float* __restrict__ FGb1, const float* __restrict__ FGw2,
    const float* __restrict__ FGb2, const float* __restrict__ DGW1,
    const float* __restrict__ DGb1, const float* __restrict__ DGw2,
    const float* __restrict__ DGb2, float* __restrict__ alphaA,
    float* __restrict__ etaA) {
  __shared__ float sA[8], sE[8];
  const int t = blockIdx.x, tid = threadIdx.x;
  const int b = tid >> 6, lane = tid & 63;
  const bool isFG = lane < 32;
  const int h = lane & 31;
  const float* xr = x + ((size_t)b * S_LEN + t) * D_DIM;
  const float* Wr = (isFG ? FGW1 : DGW1) + (size_t)h * D_DIM;
  float acc = 0.f;
  for (int d = 0; d < D_DIM; d += 4) {
    float4 xv = *(const float4*)(xr + d);
    float4 wv = *(const float4*)(Wr + d);
    acc = fmaf(xv.x, wv.x, acc);
    acc = fmaf(xv.y, wv.y, acc);
    acc = fmaf(xv.z, wv.z, acc);
    acc = fmaf(xv.w, wv.w, acc);
  }
  float z = acc + (isFG ? FGb1[h] : DGb1[h]);
  float sg = 1.f / (1.f + expf(-z));
  float p = z * sg * (isFG ? FGw2[h] : DGw2[h]);
#pragma unroll
  for (int off = 16; off > 0; off >>= 1) p += __shfl_xor(p, off, 64);
  if (lane == 0) sA[b] = 1.f / (1.f + expf(-(p + FGb2[0])));
  if (lane == 32) sE[b] = 1.f / (1.f + expf(-(p + DGb2[0])));
  __syncthreads();
  if (tid == 0) {
    float sa = 0.f, se = 0.f;
#pragma unroll
    for (int i = 0; i < 8; ++i) { sa += sA[i]; se += sE[i]; }
    alphaA[t] = sa * 0.125f;
    etaA[t] = se * 0.125f;
  }
}

// ---------------------------------------------------------------------------
// helpers: 12-float register slice <-> global (3x float4)
// ---------------------------------------------------------------------------
__device__ __forceinline__ void load12(const float* __restrict__ p, float* d) {
  float4 a = ((const float4*)p)[0], b = ((const float4*)p)[1],
         c = ((const float4*)p)[2];
  d[0]=a.x; d[1]=a.y; d[2]=a.z; d[3]=a.w;
  d[4]=b.x; d[5]=b.y; d[6]=b.z; d[7]=b.w;
  d[8]=c.x; d[9]=c.y; d[10]=c.z; d[11]=c.w;
}
__device__ __forceinline__ void store12(float* __restrict__ p, const float* s) {
  ((float4*)p)[0] = make_float4(s[0], s[1], s[2], s[3]);
  ((float4*)p)[1] = make_float4(s[4], s[5], s[6], s[7]);
  ((float4*)p)[2] = make_float4(s[8], s[9], s[10], s[11]);
}

// ---------------------------------------------------------------------------
// init_state: copy M params into mutable state, build W2^T, zero momenta.
// grid 768 (row j) x 256 thr.
// ---------------------------------------------------------------------------
__global__ __launch_bounds__(256) void init_state(
    const float* __restrict__ MW1, const float* __restrict__ Mb1,
    const float* __restrict__ MW2, const float* __restrict__ Mb2,
    float* __restrict__ W1g, float* __restrict__ S1g, float* __restrict__ W2g,
    float* __restrict__ S2g, float* __restrict__ W2Tg,
    float* __restrict__ S2Tg, float* __restrict__ b1g,
    float* __restrict__ sb1g, float* __restrict__ b2g,
    float* __restrict__ sb2g) {
  const int j = blockIdx.x, tid = threadIdx.x;
  for (int c = tid; c < 768; c += 256) {
    size_t o = (size_t)j * 768 + c;
    W1g[o] = MW1[o]; S1g[o] = 0.f;
    W2g[o] = MW2[o]; S2g[o] = 0.f;
    W2Tg[o] = MW2[(size_t)c * 768 + j]; S2Tg[o] = 0.f;
  }
  if (j == 0) {
    for (int c = tid; c < 768; c += 256) {
      b1g[c] = Mb1[c]; sb1g[c] = 0.f;
      b2g[c] = Mb2[c]; sb2g[c] = 0.f;
    }
  }
}

// ---------------------------------------------------------------------------
// step_CA(t): [C of step t-1, if t>0] then [A of step t, if t<S].
// 96 WGs x 8 waves; wave owns row jg of W1/S1 and W2T/S2T. Lane owns 12 cols.
// C: dh1[b,jg] = sum_i dOut[b,i]*W2T[jg,i]; dpre = dh1*silu'(z_prev);
//    update W2T row (dOut slice x h1_prev[b,jg]), W1 row (dpre x k_prev), b1.
//    (W2Tg still holds W2_{t-1}^T here: its update happens in this kernel,
//     after dh1 is computed -- matches the reference's use of forward weights)
// A: z[b] = k_t[b,:] . W1row + b1 (post-update); h1 = silu(z); store z, h1.
// ---------------------------------------------------------------------------
__global__ __launch_bounds__(NTHR_S) void step_CA(
    int t, const float* __restrict__ kbuf, const float* __restrict__ alphaA,
    const float* __restrict__ etaA, float* __restrict__ W1g,
    float* __restrict__ S1g, float* __restrict__ W2Tg,
    float* __restrict__ S2Tg, float* __restrict__ b1g,
    float* __restrict__ sb1g, float* __restrict__ h1g, float* __restrict__ zg,
    const float* __restrict__ dOg) {
  const int wv = threadIdx.x >> 6, lane = threadIdx.x & 63;
  const int jg = blockIdx.x * 8 + wv;
  const int colb = lane * 12;
  const size_t rowo = (size_t)jg * 768 + colb;

  alignas(16) float w1v[12];
  load12(W1g + rowo, w1v);
  float b1v = b1g[jg];

  if (t > 0) {
    const float a_t = alphaA[t - 1], e_t = etaA[t - 1];
    const float om_a = 1.f - a_t;

    alignas(16) float dc[8][12];
#pragma unroll
    for (int b = 0; b < 8; ++b) load12(dOg + b * 768 + colb, dc[b]);
    alignas(16) float w2t[12], s2t[12];
    load12(W2Tg + rowo, w2t);
    load12(S2Tg + rowo, s2t);

    float acc[8] = {0, 0, 0, 0, 0, 0, 0, 0};
#pragma unroll
    for (int m = 0; m < 12; ++m)
#pragma unroll
      for (int b = 0; b < 8; ++b) acc[b] = fmaf(dc[b][m], w2t[m], acc[b]);
#pragma unroll
    for (int off = 32; off > 0; off >>= 1)
#pragma unroll
      for (int b = 0; b < 8; ++b) acc[b] += __shfl_xor(acc[b], off, 64);

    float dpre[8], hp[8];
#pragma unroll
    for (int b = 0; b < 8; ++b) {
      float z = zg[b * 768 + jg];
      float sg = 1.f / (1.f + expf(-z));
      dpre[b] = acc[b] * (sg * (1.f + z * (1.f - sg)));
      hp[b] = h1g[b * 768 + jg];
    }

    // W2T row update: grad[jg,i] = sum_b dOut[b,i] * h1_prev[b,jg]
#pragma unroll
    for (int m = 0; m < 12; ++m) {
      float g = 0.f;
#pragma unroll
      for (int b = 0; b < 8; ++b) g = fmaf(hp[b], dc[b][m], g);
      float sn = e_t * s2t[m] - THETA_F * g;
      s2t[m] = sn;
      w2t[m] = om_a * w2t[m] + sn;
    }
    store12(W2Tg + rowo, w2t);
    store12(S2Tg + rowo, s2t);

    // W1 row update: grad[jg,m] = sum_b dpre[b] * k_prev[b,m]
    alignas(16) float kp[8][12];
#pragma unroll
    for (int b = 0; b < 8; ++b)
      load12(kbuf + ((size_t)(t - 1) * 8 + b) * 768 + colb, kp[b]);
    alignas(16) float s1[12];
    load12(S1g + rowo, s1);
#pragma unroll
    for (int m = 0; m < 12; ++m) {
      float g = 0.f;
#pragma unroll
      for (int b = 0; b < 8; ++b) g = fmaf(dpre[b], kp[b][m], g);
      float sn = e_t * s1[m] - THETA_F * g;
      s1[m] = sn;
      w1v[m] = om_a * w1v[m] + sn;
    }
    store12(W1g + rowo, w1v);
    store12(S1g + rowo, s1);

    if (lane == 0) {
      float gb = dpre[0] + dpre[1] + dpre[2] + dpre[3] + dpre[4] + dpre[5] +
                 dpre[6] + dpre[7];
      float sn = e_t * sb1g[jg] - THETA_F * gb;
      sb1g[jg] = sn;
      b1v = om_a * b1v + sn;
      b1g[jg] = b1v;
    }
    b1v = __shfl(b1v, 0, 64);
  }

  if (t < S_LEN) {
    alignas(16) float kt[8][12];
#pragma unroll
    for (int b = 0; b < 8; ++b)
      load12(kbuf + ((size_t)t * 8 + b) * 768 + colb, kt[b]);
    float acc[8] = {0, 0, 0, 0, 0, 0, 0, 0};
#pragma unroll
    for (int m = 0; m < 12; ++m)
#pragma unroll
      for (int b = 0; b < 8; ++b) acc[b] = fmaf(kt[b][m], w1v[m], acc[b]);
#pragma unroll
    for (int off = 32; off > 0; off >>= 1)
#pragma unroll
      for (int b = 0; b < 8; ++b) acc[b] += __shfl_xor(acc[b], off, 64);
#pragma unroll
    for (int b = 0; b < 8; ++b) {
      float z = acc[b] + b1v;
      float sg = 1.f / (1.f + expf(-z));
      if (lane == b) {
        zg[b * 768 + jg] = z;
        h1g[b * 768 + jg] = z * sg;
      }
    }
  }
}

// ---------------------------------------------------------------------------
// step_B(t): out[b] = h1 . W2row + b2; dOut = c0*(out - v_t); store dOg;
// update W2 row (rank-8), b2. Uses pre-update W2 for out (reference order).
// ---------------------------------------------------------------------------
__global__ __launch_bounds__(NTHR_S) void step_B(
    int t, const float* __restrict__ vbuf, const float* __restrict__ alphaA,
    const float* __restrict__ etaA, float* __restrict__ W2g,
    float* __restrict__ S2g, float* __restrict__ b2g,
    float* __restrict__ sb2g, const float* __restrict__ h1g,
    float* __restrict__ dOg) {
  const int wv = threadIdx.x >> 6, lane = threadIdx.x & 63;
  const int jg = blockIdx.x * 8 + wv;
  const int colb = lane * 12;
  const size_t rowo = (size_t)jg * 768 + colb;
  const float a_t = alphaA[t], e_t = etaA[t];
  const float om_a = 1.f - a_t;
  const float c0 = 2.0f / 6144.0f;

  alignas(16) float w2[12], s2[12];
  load12(W2g + rowo, w2);
  load12(S2g + rowo, s2);
  alignas(16) float hc[8][12];
#pragma unroll
  for (int b = 0; b < 8; ++b) load12(h1g + b * 768 + colb, hc[b]);

  float acc[8] = {0, 0, 0, 0, 0, 0, 0, 0};
#pragma unroll
  for (int m = 0; m < 12; ++m)
#pragma unroll
    for (int b = 0; b < 8; ++b) acc[b] = fmaf(hc[b][m], w2[m], acc[b]);
#pragma unroll
  for (int off = 32; off > 0; off >>= 1)
#pragma unroll
    for (int b = 0; b < 8; ++b) acc[b] += __shfl_xor(acc[b], off, 64);

  const float b2v = b2g[jg];
  float dOv[8];
#pragma unroll
  for (int b = 0; b < 8; ++b) {
    float outv = acc[b] + b2v;
    dOv[b] = c0 * (outv - vbuf[((size_t)t * 8 + b) * 768 + jg]);
    if (lane == b) dOg[b * 768 + jg] = dOv[b];
  }
#pragma unroll
  for (int m = 0; m < 12; ++m) {
    float g = 0.f;
#pragma unroll
    for (int b = 0; b < 8; ++b) g = fmaf(dOv[b], hc[b][m], g);
    float sn = e_t * s2[m] - THETA_F * g;
    s2[m] = sn;
    w2[m] = om_a * w2[m] + sn;
  }
  store12(W2g + rowo, w2);
  store12(S2g + rowo, s2);
  if (lane == 0) {
    float gb = dOv[0] + dOv[1] + dOv[2] + dOv[3] + dOv[4] + dOv[5] + dOv[6] +
               dOv[7];
    float sn = e_t * sb2g[jg] - THETA_F * gb;
    sb2g[jg] = sn;
    b2g[jg] = om_a * b2v + sn;
  }
}

// ---------------------------------------------------------------------------
extern "C" void kernel_launch(void* const* d_in, const int* in_sizes, int n_in,
                              void* d_out, int out_size, void* d_ws,
                              size_t ws_size, hipStream_t stream) {
  (void)in_sizes; (void)n_in; (void)out_size; (void)ws_size;
  const float* x   = (const float*)d_in[0];
  const float* WKw = (const float*)d_in[1];
  const float* WKb = (const float*)d_in[2];
  const float* WVw = (const float*)d_in[3];
  const float* WVb = (const float*)d_in[4];
  const float* WQw = (const float*)d_in[5];
  const float* WQb = (const float*)d_in[6];
  const float* MW1 = (const float*)d_in[7];
  const float* Mb1 = (const float*)d_in[8];
  const float* MW2 = (const float*)d_in[9];
  const float* Mb2 = (const float*)d_in[10];
  const float* FGW1 = (const float*)d_in[11];
  const float* FGb1 = (const float*)d_in[12];
  const float* FGw2 = (const float*)d_in[13];
  const float* FGb2 = (const float*)d_in[14];
  const float* DGW1 = (const float*)d_in[15];
  const float* DGb1 = (const float*)d_in[16];
  const float* DGw2 = (const float*)d_in[17];
  const float* DGb2 = (const float*)d_in[18];
  float* out = (float*)d_out;

  // workspace layout (f32). k/v live through the scan; q & h1q alias them
  // afterwards (x is never modified). Total ~16.1M f32 ~= 64.6 MB.
  float* ws = (float*)d_ws;
  float* kbuf = ws;                         // [S,B,D]
  float* vbuf = kbuf + 6291456;             // [S,B,D]
  float* W1g  = vbuf + 6291456;             // [768,768]
  float* S1g  = W1g + 589824;
  float* W2g  = S1g + 589824;
  float* S2g  = W2g + 589824;
  float* W2Tg = S2g + 589824;
  float* S2Tg = W2Tg + 589824;
  float* b1g  = S2Tg + 589824;              // [768] x4
  float* sb1g = b1g + 768;
  float* b2g  = sb1g + 768;
  float* sb2g = b2g + 768;
  float* alphaA = sb2g + 768;               // [1024] x2
  float* etaA   = alphaA + 1024;
  float* h1g  = etaA + 1024;                // [8,768] x3
  float* zg   = h1g + 6144;
  float* dOg  = zg + 6144;
  float* qbuf = kbuf;                       // alias after scan
  float* h1q  = vbuf;                       // alias after scan

  dim3 gg(12, 64), bb(256);
  gemm_tn<0, 1><<<gg, bb, 0, stream>>>(x, WKw, WKb, kbuf);
  gemm_tn<0, 1><<<gg, bb, 0, stream>>>(x, WVw, WVb, vbuf);
  gates_kernel<<<dim3(1024), dim3(512), 0, stream>>>(
      x, FGW1, FGb1, FGw2, FGb2, DGW1, DGb1, DGw2, DGb2, alphaA, etaA);
  init_state<<<dim3(768), dim3(256), 0, stream>>>(
      MW1, Mb1, MW2, Mb2, W1g, S1g, W2g, S2g, W2Tg, S2Tg, b1g, sb1g, b2g,
      sb2g);

  for (int t = 0; t < S_LEN; ++t) {
    step_CA<<<dim3(NWG_S), dim3(NTHR_S), 0, stream>>>(
        t, kbuf, alphaA, etaA, W1g, S1g, W2Tg, S2Tg, b1g, sb1g, h1g, zg, dOg);
    step_B<<<dim3(NWG_S), dim3(NTHR_S), 0, stream>>>(
        t, vbuf, alphaA, etaA, W2g, S2g, b2g, sb2g, h1g, dOg);
  }
  // final C (folds step t=1023's W1/b1/W2T update; A part skipped)
  step_CA<<<dim3(NWG_S), dim3(NTHR_S), 0, stream>>>(
      S_LEN, kbuf, alphaA, etaA, W1g, S1g, W2Tg, S2Tg, b1g, sb1g, h1g, zg,
      dOg);

  // retrieval: out = W2 @ silu(W1 @ q + b1) + b2
  gemm_tn<0, 0><<<gg, bb, 0, stream>>>(x, WQw, WQb, qbuf);
  gemm_tn<1, 0><<<gg, bb, 0, stream>>>(qbuf, W1g, b1g, h1q);
  gemm_tn<0, 0><<<gg, bb, 0, stream>>>(h1q, W2g, b2g, out);
}